// Round 3
// baseline (346.703 us; speedup 1.0000x reference)
//
#include <hip/hip_runtime.h>
#include <stdint.h>

typedef __bf16 bf16x8 __attribute__((ext_vector_type(8)));
typedef float f32x4 __attribute__((ext_vector_type(4)));
typedef unsigned short u16;

__device__ __forceinline__ u16 f2b(float f) {
  union { float f; uint32_t u; } a; a.f = f;
  return (u16)((a.u + 0x7FFFu + ((a.u >> 16) & 1u)) >> 16);  // RNE
}
__device__ __forceinline__ float b2f(u16 b) {
  union { uint32_t u; float f; } a; a.u = ((uint32_t)b) << 16; return a.f;
}

// ---------------- f32 -> bf16 convert (4 elems/thread) ----------------
__global__ void cvt_kernel(const float* __restrict__ in, u16* __restrict__ out, int n4) {
  int i = blockIdx.x * 256 + threadIdx.x;
  if (i >= n4) return;
  float4 v = reinterpret_cast<const float4*>(in)[i];
  ushort4 o;
  o.x = f2b(v.x); o.y = f2b(v.y); o.z = f2b(v.z); o.w = f2b(v.w);
  reinterpret_cast<ushort4*>(out)[i] = o;
}

// ---------------- bf16 MFMA GEMM: C[m,n] = sum_k A[m,k]*Bt[n,k] ----------------
#define BM 128
#define BN 128
#define BKK 32
#define LDT 40   // padded LDS row stride (elements) -> conflict-free ds_read_b128

template<bool PROJ>
__global__ __launch_bounds__(256) void gemm_bt(
    const u16* __restrict__ A, const u16* __restrict__ Bt,
    u16* __restrict__ Cb, float* __restrict__ Cf, const float* __restrict__ bias,
    int N, int K)
{
  __shared__ __align__(16) u16 As[BM * LDT];
  __shared__ __align__(16) u16 Bs[BN * LDT];
  const int tid = threadIdx.x;
  const int lane = tid & 63;
  const int wid = tid >> 6;
  const int wm = wid >> 1, wn = wid & 1;
  const size_t bm = (size_t)blockIdx.x * BM;
  const size_t bn = (size_t)blockIdx.y * BN;

  f32x4 acc[4][4] = {};
  const int fr = lane & 15;
  const int fk = (lane >> 4) * 8;

  const int r0 = tid >> 2, c0 = (tid & 3) * 8;
  const int r1 = r0 + 64;

  const u16* Arow0 = A + (bm + r0) * (size_t)K + c0;
  const u16* Arow1 = A + (bm + r1) * (size_t)K + c0;
  const u16* Brow0 = Bt + (bn + r0) * (size_t)K + c0;
  const u16* Brow1 = Bt + (bn + r1) * (size_t)K + c0;

  for (int k0 = 0; k0 < K; k0 += BKK) {
    uint4 a0 = *reinterpret_cast<const uint4*>(Arow0 + k0);
    uint4 a1 = *reinterpret_cast<const uint4*>(Arow1 + k0);
    uint4 b0 = *reinterpret_cast<const uint4*>(Brow0 + k0);
    uint4 b1 = *reinterpret_cast<const uint4*>(Brow1 + k0);
    __syncthreads();
    *reinterpret_cast<uint4*>(&As[r0 * LDT + c0]) = a0;
    *reinterpret_cast<uint4*>(&As[r1 * LDT + c0]) = a1;
    *reinterpret_cast<uint4*>(&Bs[r0 * LDT + c0]) = b0;
    *reinterpret_cast<uint4*>(&Bs[r1 * LDT + c0]) = b1;
    __syncthreads();
    bf16x8 af[4], bv[4];
#pragma unroll
    for (int m = 0; m < 4; ++m)
      af[m] = *reinterpret_cast<const bf16x8*>(&As[(wm * 64 + m * 16 + fr) * LDT + fk]);
#pragma unroll
    for (int n = 0; n < 4; ++n)
      bv[n] = *reinterpret_cast<const bf16x8*>(&Bs[(wn * 64 + n * 16 + fr) * LDT + fk]);
#pragma unroll
    for (int m = 0; m < 4; ++m)
#pragma unroll
      for (int n = 0; n < 4; ++n)
        acc[m][n] = __builtin_amdgcn_mfma_f32_16x16x32_bf16(af[m], bv[n], acc[m][n], 0, 0, 0);
  }
  const int fq = lane >> 4;
#pragma unroll
  for (int m = 0; m < 4; ++m) {
#pragma unroll
    for (int n = 0; n < 4; ++n) {
#pragma unroll
      for (int r = 0; r < 4; ++r) {
        size_t row = bm + wm * 64 + m * 16 + fq * 4 + r;
        size_t col = bn + wn * 64 + n * 16 + fr;
        float v = acc[m][n][r];
        if (PROJ) Cf[row * N + col] = v + bias[col];
        else      Cb[row * N + col] = f2b(v);
      }
    }
  }
}

// ---------------- per-pixel attention, 1 wave per pixel ----------------
// Reads fused QKV [pix][1536] (Q|K|V). lane = dim d. LDS minimized for occupancy.
__global__ __launch_bounds__(64) void attn_pixel(
    const u16* __restrict__ QKV, u16* __restrict__ Sc)
{
  struct PhA {
    float vh[8][68];    // normalized v rows (row 272B, 16B-aligned)
    float a8[64];       // head-mix attention A[h][g]
    float q2[64][12];   // q2 transposed [e][h], row 48B
  };
  // att (PV transpose half-buffer, bf16, row 144B = 16B-aligned) overlays PhA.
  __shared__ __align__(16) union { PhA A; u16 att[32][72]; } sm;
  __shared__ __align__(16) float vvs[64][12];  // vv*invl transposed [d][h]

  const int bid = blockIdx.x;
  const int pix = (bid & 7) * 2048 + (bid >> 3);   // XCD-chunked swizzle
  const int b = pix >> 12;
  const int n = pix & 4095;
  const int lane = threadIdx.x;
  const size_t base = (size_t)pix * 1536 + lane;

  float qv[8], kv[8], vv[8];
#pragma unroll
  for (int h = 0; h < 8; ++h) {
    qv[h] = b2f(QKV[base + h * 64]);
    kv[h] = b2f(QKV[base + 512 + h * 64]);
    vv[h] = 2.0f * b2f(QKV[base + 1024 + h * 64]);   // v = v + v
  }
  // l2 norms over 64 lanes per head; q,k stay in regs, v_h -> LDS
#pragma unroll
  for (int h = 0; h < 8; ++h) {
    float s = qv[h] * qv[h];
#pragma unroll
    for (int m = 1; m < 64; m <<= 1) s += __shfl_xor(s, m, 64);
    qv[h] *= 1.0f / fmaxf(sqrtf(s), 1e-12f);
  }
#pragma unroll
  for (int h = 0; h < 8; ++h) {
    float s = kv[h] * kv[h];
#pragma unroll
    for (int m = 1; m < 64; m <<= 1) s += __shfl_xor(s, m, 64);
    kv[h] *= 1.0f / fmaxf(sqrtf(s), 1e-12f);
  }
#pragma unroll
  for (int h = 0; h < 8; ++h) {
    float s = vv[h] * vv[h];
#pragma unroll
    for (int m = 1; m < 64; m <<= 1) s += __shfl_xor(s, m, 64);
    sm.A.vh[h][lane] = vv[h] * (1.0f / fmaxf(sqrtf(s), 1e-12f));
  }
  __syncthreads();

  // 8x8 gram of v_h; lane -> (hh,gg). |G|<=1 (unit vectors) -> exp without max.
  const int hh = lane >> 3, gg = lane & 7;
  float g = 0.0f;
#pragma unroll
  for (int i = 0; i < 64; i += 4) {
    float4 a = *reinterpret_cast<const float4*>(&sm.A.vh[hh][i]);
    float4 c = *reinterpret_cast<const float4*>(&sm.A.vh[gg][i]);
    g += a.x * c.x + a.y * c.y + a.z * c.z + a.w * c.w;
  }
  float ex = __expf(g);
  float sum = ex;
  sum += __shfl_xor(sum, 1, 64);
  sum += __shfl_xor(sum, 2, 64);
  sum += __shfl_xor(sum, 4, 64);
  sm.A.a8[lane] = ex / sum;
  __syncthreads();

  // head-mix: q2[h] = sum_g A[h][g]*q[g] (a8 rows via float4 broadcast)
  float q2r[8], k2r[8];
#pragma unroll
  for (int h = 0; h < 8; ++h) {
    float4 a0 = *reinterpret_cast<const float4*>(&sm.A.a8[h * 8]);
    float4 a1 = *reinterpret_cast<const float4*>(&sm.A.a8[h * 8 + 4]);
    q2r[h] = a0.x * qv[0] + a0.y * qv[1] + a0.z * qv[2] + a0.w * qv[3]
           + a1.x * qv[4] + a1.y * qv[5] + a1.z * qv[6] + a1.w * qv[7];
    k2r[h] = a0.x * kv[0] + a0.y * kv[1] + a0.z * kv[2] + a0.w * kv[3]
           + a1.x * kv[4] + a1.y * kv[5] + a1.z * kv[6] + a1.w * kv[7];
  }
  *reinterpret_cast<float4*>(&sm.A.q2[lane][0]) = make_float4(q2r[0], q2r[1], q2r[2], q2r[3]);
  *reinterpret_cast<float4*>(&sm.A.q2[lane][4]) = make_float4(q2r[4], q2r[5], q2r[6], q2r[7]);
  __syncthreads();

  // S[d][e] = sum_h k2[h][d]*q2[h][e]; lane = d, full e-row in regs.
  // |S| <= 8 (A rows sum to 1, unit q,k) -> exp without max-subtract is safe.
  float sv[64];
#pragma unroll
  for (int e = 0; e < 64; ++e) {
    float4 qa = *reinterpret_cast<const float4*>(&sm.A.q2[e][0]);
    float4 qb = *reinterpret_cast<const float4*>(&sm.A.q2[e][4]);
    sv[e] = k2r[0] * qa.x + k2r[1] * qa.y + k2r[2] * qa.z + k2r[3] * qa.w
          + k2r[4] * qb.x + k2r[5] * qb.y + k2r[6] * qb.z + k2r[7] * qb.w;
  }
  float l = 0.0f;
#pragma unroll
  for (int e = 0; e < 64; ++e) { sv[e] = __expf(sv[e]); l += sv[e]; }
  float invl = 1.0f / l;
  // fold 1/l[d] into vvs row (P stored as raw exp)
  *reinterpret_cast<float4*>(&vvs[lane][0]) =
      make_float4(vv[0] * invl, vv[1] * invl, vv[2] * invl, vv[3] * invl);
  *reinterpret_cast<float4*>(&vvs[lane][4]) =
      make_float4(vv[4] * invl, vv[5] * invl, vv[6] * invl, vv[7] * invl);
  __syncthreads();   // all q2 reads done before att overlays PhA

  float out[8] = {0, 0, 0, 0, 0, 0, 0, 0};
  // ---- pass 0: rows d in [0,32) ----
  if (lane < 32) {
#pragma unroll
    for (int e0 = 0; e0 < 64; e0 += 8) {
      bf16x8 w;
#pragma unroll
      for (int j = 0; j < 8; ++j) w[j] = (__bf16)sv[e0 + j];
      *reinterpret_cast<bf16x8*>(&sm.att[lane][e0]) = w;
    }
  }
  __syncthreads();
#pragma unroll
  for (int d = 0; d < 32; ++d) {
    float p = b2f(sm.att[d][lane]);
    float4 va = *reinterpret_cast<const float4*>(&vvs[d][0]);
    float4 vb = *reinterpret_cast<const float4*>(&vvs[d][4]);
    out[0] += va.x * p; out[1] += va.y * p; out[2] += va.z * p; out[3] += va.w * p;
    out[4] += vb.x * p; out[5] += vb.y * p; out[6] += vb.z * p; out[7] += vb.w * p;
  }
  __syncthreads();
  // ---- pass 1: rows d in [32,64) ----
  if (lane >= 32) {
#pragma unroll
    for (int e0 = 0; e0 < 64; e0 += 8) {
      bf16x8 w;
#pragma unroll
      for (int j = 0; j < 8; ++j) w[j] = (__bf16)sv[e0 + j];
      *reinterpret_cast<bf16x8*>(&sm.att[lane - 32][e0]) = w;
    }
  }
  __syncthreads();
#pragma unroll
  for (int d = 0; d < 32; ++d) {
    float p = b2f(sm.att[d][lane]);
    float4 va = *reinterpret_cast<const float4*>(&vvs[d + 32][0]);
    float4 vb = *reinterpret_cast<const float4*>(&vvs[d + 32][4]);
    out[0] += va.x * p; out[1] += va.y * p; out[2] += va.z * p; out[3] += va.w * p;
    out[4] += vb.x * p; out[5] += vb.y * p; out[6] += vb.z * p; out[7] += vb.w * p;
  }

  // scramble store: scr[b][e*64 + n/64][(n%64)*8 + h], e = lane (16B/lane)
  uint32_t p0 = (uint32_t)f2b(out[0]) | ((uint32_t)f2b(out[1]) << 16);
  uint32_t p1 = (uint32_t)f2b(out[2]) | ((uint32_t)f2b(out[3]) << 16);
  uint32_t p2 = (uint32_t)f2b(out[4]) | ((uint32_t)f2b(out[5]) << 16);
  uint32_t p3 = (uint32_t)f2b(out[6]) | ((uint32_t)f2b(out[7]) << 16);
  uint4 pk; pk.x = p0; pk.y = p1; pk.z = p2; pk.w = p3;
  size_t doff = (size_t)b * 2097152 + ((size_t)lane * 64 + (size_t)(n >> 6)) * 512
              + (size_t)(n & 63) * 8;
  *reinterpret_cast<uint4*>(Sc + doff) = pk;
}

// ---------------- launcher ----------------
extern "C" void kernel_launch(void* const* d_in, const int* in_sizes, int n_in,
                              void* d_out, int out_size, void* d_ws, size_t ws_size,
                              hipStream_t stream) {
  const float* x  = (const float*)d_in[0];
  const float* Wq = (const float*)d_in[1];
  const float* Wk = (const float*)d_in[2];
  const float* Wv = (const float*)d_in[3];
  const float* Pw = (const float*)d_in[5];
  const float* Pb = (const float*)d_in[6];
  float* out = (float*)d_out;

  const size_t MK = 16384ull * 512ull;
  u16* Xb   = (u16*)d_ws;          // 16.8 MB
  u16* QKVb = Xb + MK;             // 50.3 MB (fused [16384][1536])
  u16* Scr  = QKVb + 3 * MK;       // 16.8 MB
  u16* Wcat = Scr + MK;            // 1.5 MB ([1536][512] = Wq|Wk|Wv stacked)
  u16* Pwb  = Wcat + 3 * 262144;   // 0.5 MB

  cvt_kernel<<<8192, 256, 0, stream>>>(x,  Xb,   2097152);
  cvt_kernel<<<256,  256, 0, stream>>>(Wq, Wcat,          65536);
  cvt_kernel<<<256,  256, 0, stream>>>(Wk, Wcat + 262144, 65536);
  cvt_kernel<<<256,  256, 0, stream>>>(Wv, Wcat + 524288, 65536);
  cvt_kernel<<<256,  256, 0, stream>>>(Pw, Pwb,           65536);

  dim3 gq(128, 12);   // fused QKV: M=16384, N=1536, K=512
  gemm_bt<false><<<gq, 256, 0, stream>>>(Xb, Wcat, QKVb, nullptr, nullptr, 1536, 512);

  attn_pixel<<<16384, 64, 0, stream>>>(QKVb, Scr);

  dim3 gp(128, 4);
  gemm_bt<true><<<gp, 256, 0, stream>>>(Scr, Pwb, nullptr, out, Pb, 512, 512);
}

// Round 4
// 308.403 us; speedup vs baseline: 1.1242x; 1.1242x over previous
//
#include <hip/hip_runtime.h>
#include <stdint.h>

typedef __bf16 bf16x8 __attribute__((ext_vector_type(8)));
typedef float f32x4 __attribute__((ext_vector_type(4)));
typedef unsigned short u16;

__device__ __forceinline__ u16 f2b(float f) {
  union { float f; uint32_t u; } a; a.f = f;
  return (u16)((a.u + 0x7FFFu + ((a.u >> 16) & 1u)) >> 16);  // RNE
}
__device__ __forceinline__ float b2f(u16 b) {
  union { uint32_t u; float f; } a; a.u = ((uint32_t)b) << 16; return a.f;
}

// ---------------- f32 -> bf16 convert (4 elems/thread) ----------------
__global__ void cvt_kernel(const float* __restrict__ in, u16* __restrict__ out, int n4) {
  int i = blockIdx.x * 256 + threadIdx.x;
  if (i >= n4) return;
  float4 v = reinterpret_cast<const float4*>(in)[i];
  ushort4 o;
  o.x = f2b(v.x); o.y = f2b(v.y); o.z = f2b(v.z); o.w = f2b(v.w);
  reinterpret_cast<ushort4*>(out)[i] = o;
}

// ---------------- bf16 MFMA GEMM: C[m,n] = sum_k A[m,k]*Bt[n,k] ----------------
// grid = (N/BN, M/BM): consecutive blocks share the A-panel (L2-resident).
#define BM 128
#define BN 128
#define BKK 32
#define LDT 40   // padded LDS row stride -> conflict-free ds_read_b128

template<bool PROJ>
__global__ __launch_bounds__(256) void gemm_bt(
    const u16* __restrict__ A, const u16* __restrict__ Bt,
    u16* __restrict__ Cb, float* __restrict__ Cf, const float* __restrict__ bias,
    int N, int K)
{
  __shared__ __align__(16) u16 As[BM * LDT];
  __shared__ __align__(16) u16 Bs[BN * LDT];
  const int tid = threadIdx.x;
  const int lane = tid & 63;
  const int wid = tid >> 6;
  const int wm = wid >> 1, wn = wid & 1;
  const size_t bm = (size_t)blockIdx.y * BM;
  const size_t bn = (size_t)blockIdx.x * BN;

  f32x4 acc[4][4] = {};
  const int fr = lane & 15;
  const int fk = (lane >> 4) * 8;

  const int r0 = tid >> 2, c0 = (tid & 3) * 8;
  const int r1 = r0 + 64;

  const u16* Arow0 = A + (bm + r0) * (size_t)K + c0;
  const u16* Arow1 = A + (bm + r1) * (size_t)K + c0;
  const u16* Brow0 = Bt + (bn + r0) * (size_t)K + c0;
  const u16* Brow1 = Bt + (bn + r1) * (size_t)K + c0;

  for (int k0 = 0; k0 < K; k0 += BKK) {
    uint4 a0 = *reinterpret_cast<const uint4*>(Arow0 + k0);
    uint4 a1 = *reinterpret_cast<const uint4*>(Arow1 + k0);
    uint4 b0 = *reinterpret_cast<const uint4*>(Brow0 + k0);
    uint4 b1 = *reinterpret_cast<const uint4*>(Brow1 + k0);
    __syncthreads();
    *reinterpret_cast<uint4*>(&As[r0 * LDT + c0]) = a0;
    *reinterpret_cast<uint4*>(&As[r1 * LDT + c0]) = a1;
    *reinterpret_cast<uint4*>(&Bs[r0 * LDT + c0]) = b0;
    *reinterpret_cast<uint4*>(&Bs[r1 * LDT + c0]) = b1;
    __syncthreads();
    bf16x8 af[4], bv[4];
#pragma unroll
    for (int m = 0; m < 4; ++m)
      af[m] = *reinterpret_cast<const bf16x8*>(&As[(wm * 64 + m * 16 + fr) * LDT + fk]);
#pragma unroll
    for (int n = 0; n < 4; ++n)
      bv[n] = *reinterpret_cast<const bf16x8*>(&Bs[(wn * 64 + n * 16 + fr) * LDT + fk]);
#pragma unroll
    for (int m = 0; m < 4; ++m)
#pragma unroll
      for (int n = 0; n < 4; ++n)
        acc[m][n] = __builtin_amdgcn_mfma_f32_16x16x32_bf16(af[m], bv[n], acc[m][n], 0, 0, 0);
  }
  const int fq = lane >> 4;
#pragma unroll
  for (int m = 0; m < 4; ++m) {
#pragma unroll
    for (int n = 0; n < 4; ++n) {
#pragma unroll
      for (int r = 0; r < 4; ++r) {
        size_t row = bm + wm * 64 + m * 16 + fq * 4 + r;
        size_t col = bn + wn * 64 + n * 16 + fr;
        float v = acc[m][n][r];
        if (PROJ) Cf[row * N + col] = v + bias[col];
        else      Cb[row * N + col] = f2b(v);
      }
    }
  }
}

// ---------------- per-pixel attention, 1 wave per pixel ----------------
// lane = dim index. Stage 2: lane = e (output col); P never materialized.
__global__ __launch_bounds__(64) void attn_pixel(
    const u16* __restrict__ QKV, u16* __restrict__ Sc)
{
  __shared__ __align__(16) union {
    float vh[8][68];                              // phase A: normalized v rows
    struct { float k2s[64][12]; float vvs[64][12]; } B;  // stage 2 (6144B)
  } sm;
  __shared__ __align__(16) float a8[64];          // head-mix attention A[h][g]

  const int bid = blockIdx.x;
  const int pix = (bid & 7) * 2048 + (bid >> 3);  // XCD-chunked swizzle
  const int b = pix >> 12;
  const int n = pix & 4095;
  const int lane = threadIdx.x;
  const size_t base = (size_t)pix * 1536 + lane;

  float qv[8], kv[8], vv[8];
#pragma unroll
  for (int h = 0; h < 8; ++h) {
    qv[h] = b2f(QKV[base + h * 64]);
    kv[h] = b2f(QKV[base + 512 + h * 64]);
    vv[h] = 2.0f * b2f(QKV[base + 1024 + h * 64]);   // v = v + v
  }
  // vvs region doesn't overlap vh: write early
  *reinterpret_cast<float4*>(&sm.B.vvs[lane][0]) = make_float4(vv[0], vv[1], vv[2], vv[3]);
  *reinterpret_cast<float4*>(&sm.B.vvs[lane][4]) = make_float4(vv[4], vv[5], vv[6], vv[7]);

  // l2 norms across 64 lanes per head
#pragma unroll
  for (int h = 0; h < 8; ++h) {
    float s = qv[h] * qv[h];
#pragma unroll
    for (int m = 1; m < 64; m <<= 1) s += __shfl_xor(s, m, 64);
    qv[h] *= 1.0f / fmaxf(sqrtf(s), 1e-12f);
  }
#pragma unroll
  for (int h = 0; h < 8; ++h) {
    float s = kv[h] * kv[h];
#pragma unroll
    for (int m = 1; m < 64; m <<= 1) s += __shfl_xor(s, m, 64);
    kv[h] *= 1.0f / fmaxf(sqrtf(s), 1e-12f);
  }
#pragma unroll
  for (int h = 0; h < 8; ++h) {
    float s = vv[h] * vv[h];
#pragma unroll
    for (int m = 1; m < 64; m <<= 1) s += __shfl_xor(s, m, 64);
    sm.vh[h][lane] = vv[h] * (1.0f / fmaxf(sqrtf(s), 1e-12f));
  }
  __syncthreads();

  // 8x8 gram of v_h; lane -> (hh,gg). |G|<=1 -> exp without max-subtract.
  const int hh = lane >> 3, gg = lane & 7;
  float g = 0.0f;
#pragma unroll
  for (int i = 0; i < 64; i += 4) {
    float4 a = *reinterpret_cast<const float4*>(&sm.vh[hh][i]);
    float4 c = *reinterpret_cast<const float4*>(&sm.vh[gg][i]);
    g += a.x * c.x + a.y * c.y + a.z * c.z + a.w * c.w;
  }
  float ex = __expf(g);
  float sum = ex;
  sum += __shfl_xor(sum, 1, 64);
  sum += __shfl_xor(sum, 2, 64);
  sum += __shfl_xor(sum, 4, 64);
  a8[lane] = ex / sum;
  __syncthreads();

  // head-mix: q2[h][lane] = sum_g A[h][g]*q[g][lane]; same for k
  float q2r[8], k2r[8];
#pragma unroll
  for (int h = 0; h < 8; ++h) {
    float4 a0 = *reinterpret_cast<const float4*>(&a8[h * 8]);
    float4 a1 = *reinterpret_cast<const float4*>(&a8[h * 8 + 4]);
    q2r[h] = a0.x * qv[0] + a0.y * qv[1] + a0.z * qv[2] + a0.w * qv[3]
           + a1.x * qv[4] + a1.y * qv[5] + a1.z * qv[6] + a1.w * qv[7];
    k2r[h] = a0.x * kv[0] + a0.y * kv[1] + a0.z * kv[2] + a0.w * kv[3]
           + a1.x * kv[4] + a1.y * kv[5] + a1.z * kv[6] + a1.w * kv[7];
  }
  // k2 transposed to LDS (overlaps dead vh; all vh reads completed pre-barrier)
  __syncthreads();
  *reinterpret_cast<float4*>(&sm.B.k2s[lane][0]) = make_float4(k2r[0], k2r[1], k2r[2], k2r[3]);
  *reinterpret_cast<float4*>(&sm.B.k2s[lane][4]) = make_float4(k2r[4], k2r[5], k2r[6], k2r[7]);
  __syncthreads();

  // Stage 2, lane = e. S[d][e] = sum_h k2[h][d]*q2[h][e]; |S|<=8 -> no max-sub.
  // P[d][e] = exp(S)/l[d]; out[h][e] = sum_d vv[h][d]*P[d][e]  (all in-lane).
  float out[8] = {0, 0, 0, 0, 0, 0, 0, 0};
#pragma unroll
  for (int d0 = 0; d0 < 64; d0 += 8) {
    float p[8];
#pragma unroll
    for (int j = 0; j < 8; ++j) {
      const int d = d0 + j;
      float4 ka = *reinterpret_cast<const float4*>(&sm.B.k2s[d][0]);
      float4 kb = *reinterpret_cast<const float4*>(&sm.B.k2s[d][4]);
      float s = ka.x * q2r[0] + ka.y * q2r[1] + ka.z * q2r[2] + ka.w * q2r[3]
              + kb.x * q2r[4] + kb.y * q2r[5] + kb.z * q2r[6] + kb.w * q2r[7];
      p[j] = __expf(s);
    }
#pragma unroll
    for (int j = 0; j < 8; ++j) {
      const int d = d0 + j;
      float t = p[j];
      t += __shfl_xor(t, 1, 64);
      t += __shfl_xor(t, 2, 64);
      t += __shfl_xor(t, 4, 64);
      t += __shfl_xor(t, 8, 64);
      t += __shfl_xor(t, 16, 64);
      t += __shfl_xor(t, 32, 64);
      float ip = p[j] * __builtin_amdgcn_rcpf(t);   // l[d] uniform; rcp err ~1e-7
      float4 va = *reinterpret_cast<const float4*>(&sm.B.vvs[d][0]);
      float4 vb = *reinterpret_cast<const float4*>(&sm.B.vvs[d][4]);
      out[0] += va.x * ip; out[1] += va.y * ip; out[2] += va.z * ip; out[3] += va.w * ip;
      out[4] += vb.x * ip; out[5] += vb.y * ip; out[6] += vb.z * ip; out[7] += vb.w * ip;
    }
  }

  // scramble store: scr[b][e*64 + n/64][(n%64)*8 + h], e = lane (16B/lane)
  uint32_t p0 = (uint32_t)f2b(out[0]) | ((uint32_t)f2b(out[1]) << 16);
  uint32_t p1 = (uint32_t)f2b(out[2]) | ((uint32_t)f2b(out[3]) << 16);
  uint32_t p2 = (uint32_t)f2b(out[4]) | ((uint32_t)f2b(out[5]) << 16);
  uint32_t p3 = (uint32_t)f2b(out[6]) | ((uint32_t)f2b(out[7]) << 16);
  uint4 pk; pk.x = p0; pk.y = p1; pk.z = p2; pk.w = p3;
  size_t doff = (size_t)b * 2097152 + ((size_t)lane * 64 + (size_t)(n >> 6)) * 512
              + (size_t)(n & 63) * 8;
  *reinterpret_cast<uint4*>(Sc + doff) = pk;
}

// ---------------- launcher ----------------
extern "C" void kernel_launch(void* const* d_in, const int* in_sizes, int n_in,
                              void* d_out, int out_size, void* d_ws, size_t ws_size,
                              hipStream_t stream) {
  const float* x  = (const float*)d_in[0];
  const float* Wq = (const float*)d_in[1];
  const float* Wk = (const float*)d_in[2];
  const float* Wv = (const float*)d_in[3];
  const float* Pw = (const float*)d_in[5];
  const float* Pb = (const float*)d_in[6];
  float* out = (float*)d_out;

  const size_t MK = 16384ull * 512ull;
  u16* Xb   = (u16*)d_ws;          // 16.8 MB
  u16* QKVb = Xb + MK;             // 50.3 MB (fused [16384][1536])
  u16* Scr  = QKVb + 3 * MK;       // 16.8 MB
  u16* Wcat = Scr + MK;            // 1.5 MB ([1536][512] = Wq|Wk|Wv)
  u16* Pwb  = Wcat + 3 * 262144;   // 0.5 MB

  cvt_kernel<<<8192, 256, 0, stream>>>(x,  Xb,   2097152);
  cvt_kernel<<<256,  256, 0, stream>>>(Wq, Wcat,          65536);
  cvt_kernel<<<256,  256, 0, stream>>>(Wk, Wcat + 262144, 65536);
  cvt_kernel<<<256,  256, 0, stream>>>(Wv, Wcat + 524288, 65536);
  cvt_kernel<<<256,  256, 0, stream>>>(Pw, Pwb,           65536);

  dim3 gq(12, 128);   // fused QKV: x = N-tiles (B-walk), y = M-tiles (A-panel)
  gemm_bt<false><<<gq, 256, 0, stream>>>(Xb, Wcat, QKVb, nullptr, nullptr, 1536, 512);

  attn_pixel<<<16384, 64, 0, stream>>>(QKVb, Scr);

  dim3 gp(4, 128);
  gemm_bt<true><<<gp, 256, 0, stream>>>(Scr, Pwb, nullptr, out, Pb, 512, 512);
}

// Round 6
// 280.471 us; speedup vs baseline: 1.2361x; 1.0996x over previous
//
#include <hip/hip_runtime.h>
#include <stdint.h>

typedef __bf16 bf16x8 __attribute__((ext_vector_type(8)));
typedef float f32x4 __attribute__((ext_vector_type(4)));
typedef unsigned short u16;

__device__ __forceinline__ u16 f2b(float f) {
  union { float f; uint32_t u; } a; a.f = f;
  return (u16)((a.u + 0x7FFFu + ((a.u >> 16) & 1u)) >> 16);  // RNE
}
__device__ __forceinline__ float b2f(u16 b) {
  union { uint32_t u; float f; } a; a.u = ((uint32_t)b) << 16; return a.f;
}
__device__ __forceinline__ float blo(uint32_t w) {   // low bf16 -> f32
  union { uint32_t u; float f; } a; a.u = w << 16; return a.f;
}
__device__ __forceinline__ float bhi(uint32_t w) {   // high bf16 -> f32
  union { uint32_t u; float f; } a; a.u = w & 0xFFFF0000u; return a.f;
}

// ---------------- f32 -> bf16 convert (4 elems/thread) ----------------
__global__ void cvt_kernel(const float* __restrict__ in, u16* __restrict__ out, int n4) {
  int i = blockIdx.x * 256 + threadIdx.x;
  if (i >= n4) return;
  float4 v = reinterpret_cast<const float4*>(in)[i];
  ushort4 o;
  o.x = f2b(v.x); o.y = f2b(v.y); o.z = f2b(v.z); o.w = f2b(v.w);
  reinterpret_cast<ushort4*>(out)[i] = o;
}

// ---------------- bf16 MFMA GEMM: C[m,n] = sum_k A[m,k]*Bt[n,k] ----------------
#define BM 128
#define BN 128
#define BKK 32
#define LDT 40

template<bool PROJ>
__global__ __launch_bounds__(256) void gemm_bt(
    const u16* __restrict__ A, const u16* __restrict__ Bt,
    u16* __restrict__ Cb, float* __restrict__ Cf, const float* __restrict__ bias,
    int N, int K)
{
  __shared__ __align__(16) u16 As[BM * LDT];
  __shared__ __align__(16) u16 Bs[BN * LDT];
  const int tid = threadIdx.x;
  const int lane = tid & 63;
  const int wid = tid >> 6;
  const int wm = wid >> 1, wn = wid & 1;
  const size_t bm = (size_t)blockIdx.y * BM;
  const size_t bn = (size_t)blockIdx.x * BN;

  f32x4 acc[4][4] = {};
  const int fr = lane & 15;
  const int fk = (lane >> 4) * 8;

  const int r0 = tid >> 2, c0 = (tid & 3) * 8;
  const int r1 = r0 + 64;

  const u16* Arow0 = A + (bm + r0) * (size_t)K + c0;
  const u16* Arow1 = A + (bm + r1) * (size_t)K + c0;
  const u16* Brow0 = Bt + (bn + r0) * (size_t)K + c0;
  const u16* Brow1 = Bt + (bn + r1) * (size_t)K + c0;

  for (int k0 = 0; k0 < K; k0 += BKK) {
    uint4 a0 = *reinterpret_cast<const uint4*>(Arow0 + k0);
    uint4 a1 = *reinterpret_cast<const uint4*>(Arow1 + k0);
    uint4 b0 = *reinterpret_cast<const uint4*>(Brow0 + k0);
    uint4 b1 = *reinterpret_cast<const uint4*>(Brow1 + k0);
    __syncthreads();
    *reinterpret_cast<uint4*>(&As[r0 * LDT + c0]) = a0;
    *reinterpret_cast<uint4*>(&As[r1 * LDT + c0]) = a1;
    *reinterpret_cast<uint4*>(&Bs[r0 * LDT + c0]) = b0;
    *reinterpret_cast<uint4*>(&Bs[r1 * LDT + c0]) = b1;
    __syncthreads();
    bf16x8 af[4], bv[4];
#pragma unroll
    for (int m = 0; m < 4; ++m)
      af[m] = *reinterpret_cast<const bf16x8*>(&As[(wm * 64 + m * 16 + fr) * LDT + fk]);
#pragma unroll
    for (int n = 0; n < 4; ++n)
      bv[n] = *reinterpret_cast<const bf16x8*>(&Bs[(wn * 64 + n * 16 + fr) * LDT + fk]);
#pragma unroll
    for (int m = 0; m < 4; ++m)
#pragma unroll
      for (int n = 0; n < 4; ++n)
        acc[m][n] = __builtin_amdgcn_mfma_f32_16x16x32_bf16(af[m], bv[n], acc[m][n], 0, 0, 0);
  }
  const int fq = lane >> 4;
#pragma unroll
  for (int m = 0; m < 4; ++m) {
#pragma unroll
    for (int n = 0; n < 4; ++n) {
#pragma unroll
      for (int r = 0; r < 4; ++r) {
        size_t row = bm + wm * 64 + m * 16 + fq * 4 + r;
        size_t col = bn + wn * 64 + n * 16 + fr;
        float v = acc[m][n][r];
        if (PROJ) Cf[row * N + col] = v + bias[col];
        else      Cb[row * N + col] = f2b(v);
      }
    }
  }
}

// ---------------- per-pixel attention: 4 pixels / 256-thread block ----------------
// One wave per pixel, per-wave LDS slice, NO barriers (intra-wave ordering only).
struct SliceU {
  union { float vh[8][68]; float k2s[64][12]; } u;  // 3072 B (vh 2176 within)
  float vvs[64][12];                                // 3072 B
  float a8[64];                                     // 256 B
};                                                  // 6400 B/pixel

__global__ __launch_bounds__(256, 8) void attn_pixel(
    const u16* __restrict__ QKV, u16* __restrict__ Sc)
{
  __shared__ __align__(16) SliceU sl[4];            // 25600 B/block
  const int tid = threadIdx.x;
  const int wid = tid >> 6;
  const int lane = tid & 63;
  SliceU& S = sl[wid];

  const int bid = blockIdx.x;                       // 4096 blocks
  const int pixb = (bid & 7) * 512 + (bid >> 3);    // XCD-chunked swizzle
  const int pix = pixb * 4 + wid;
  const int b = pix >> 12;
  const int n = pix & 4095;

  // --- cheap norms: vector load in (head = lane>>3, 8 contiguous dims) mapping ---
  const u16* P = QKV + (size_t)pix * 1536;
  float nq, nk, nv;
  {
    uint4 r = *reinterpret_cast<const uint4*>(P + lane * 8);
    float s = blo(r.x)*blo(r.x) + bhi(r.x)*bhi(r.x) + blo(r.y)*blo(r.y) + bhi(r.y)*bhi(r.y)
            + blo(r.z)*blo(r.z) + bhi(r.z)*bhi(r.z) + blo(r.w)*blo(r.w) + bhi(r.w)*bhi(r.w);
    s += __shfl_xor(s, 1, 64); s += __shfl_xor(s, 2, 64); s += __shfl_xor(s, 4, 64);
    nq = s;
  }
  {
    uint4 r = *reinterpret_cast<const uint4*>(P + 512 + lane * 8);
    float s = blo(r.x)*blo(r.x) + bhi(r.x)*bhi(r.x) + blo(r.y)*blo(r.y) + bhi(r.y)*bhi(r.y)
            + blo(r.z)*blo(r.z) + bhi(r.z)*bhi(r.z) + blo(r.w)*blo(r.w) + bhi(r.w)*bhi(r.w);
    s += __shfl_xor(s, 1, 64); s += __shfl_xor(s, 2, 64); s += __shfl_xor(s, 4, 64);
    nk = s;
  }
  {
    uint4 r = *reinterpret_cast<const uint4*>(P + 1024 + lane * 8);
    float s = blo(r.x)*blo(r.x) + bhi(r.x)*bhi(r.x) + blo(r.y)*blo(r.y) + bhi(r.y)*bhi(r.y)
            + blo(r.z)*blo(r.z) + bhi(r.z)*bhi(r.z) + blo(r.w)*blo(r.w) + bhi(r.w)*bhi(r.w);
    s += __shfl_xor(s, 1, 64); s += __shfl_xor(s, 2, 64); s += __shfl_xor(s, 4, 64);
    nv = s;
  }

  // --- scalar loads in (lane = dim) mapping ---
  float qv[8], kv[8], vv[8];
#pragma unroll
  for (int h = 0; h < 8; ++h) {
    qv[h] = b2f(P[h * 64 + lane]);
    kv[h] = b2f(P[512 + h * 64 + lane]);
    vv[h] = 2.0f * b2f(P[1024 + h * 64 + lane]);   // v = v + v
  }
  // vvs (raw doubled v, transposed) -> LDS early; vv regs freed
  *reinterpret_cast<float4*>(&S.vvs[lane][0]) = make_float4(vv[0], vv[1], vv[2], vv[3]);
  *reinterpret_cast<float4*>(&S.vvs[lane][4]) = make_float4(vv[4], vv[5], vv[6], vv[7]);

  // normalize: broadcast per-head ssq via readlane; |2v| = 2*sqrt(nv)
#pragma unroll
  for (int h = 0; h < 8; ++h) {
    float sq = __shfl(nq, h * 8, 64);
    float sk = __shfl(nk, h * 8, 64);
    float sv = __shfl(nv, h * 8, 64);
    qv[h] *= 1.0f / fmaxf(sqrtf(sq), 1e-12f);
    kv[h] *= 1.0f / fmaxf(sqrtf(sk), 1e-12f);
    S.u.vh[h][lane] = vv[h] * (1.0f / fmaxf(2.0f * sqrtf(sv), 1e-12f));
  }

  // --- 8x8 gram of v_h; lane -> (hh,gg); |G|<=1 -> exp without max-sub ---
  const int hh = lane >> 3, gg = lane & 7;
  float g = 0.0f;
#pragma unroll
  for (int i = 0; i < 64; i += 4) {
    float4 a = *reinterpret_cast<const float4*>(&S.u.vh[hh][i]);
    float4 c = *reinterpret_cast<const float4*>(&S.u.vh[gg][i]);
    g += a.x * c.x + a.y * c.y + a.z * c.z + a.w * c.w;
  }
  float ex = __expf(g);
  float sum = ex;
  sum += __shfl_xor(sum, 1, 64);
  sum += __shfl_xor(sum, 2, 64);
  sum += __shfl_xor(sum, 4, 64);
  S.a8[lane] = ex / sum;

  // --- head-mix: q2[h][lane] = sum_g A[h][g]*q[g][lane]; same for k ---
  float q2r[8], k2r[8];
#pragma unroll
  for (int h = 0; h < 8; ++h) {
    float4 a0 = *reinterpret_cast<const float4*>(&S.a8[h * 8]);
    float4 a1 = *reinterpret_cast<const float4*>(&S.a8[h * 8 + 4]);
    q2r[h] = a0.x * qv[0] + a0.y * qv[1] + a0.z * qv[2] + a0.w * qv[3]
           + a1.x * qv[4] + a1.y * qv[5] + a1.z * qv[6] + a1.w * qv[7];
    k2r[h] = a0.x * kv[0] + a0.y * kv[1] + a0.z * kv[2] + a0.w * kv[3]
           + a1.x * kv[4] + a1.y * kv[5] + a1.z * kv[6] + a1.w * kv[7];
  }
  // k2 transposed into LDS (overlays vh; program order keeps it safe in-wave)
  *reinterpret_cast<float4*>(&S.u.k2s[lane][0]) = make_float4(k2r[0], k2r[1], k2r[2], k2r[3]);
  *reinterpret_cast<float4*>(&S.u.k2s[lane][4]) = make_float4(k2r[4], k2r[5], k2r[6], k2r[7]);

  // --- stage 2, lane = e; |S|<=8 -> no max-sub; P never materialized ---
  float out[8] = {0, 0, 0, 0, 0, 0, 0, 0};
#pragma unroll
  for (int d0 = 0; d0 < 64; d0 += 4) {
    float p[4];
#pragma unroll
    for (int j = 0; j < 4; ++j) {
      const int d = d0 + j;
      float4 ka = *reinterpret_cast<const float4*>(&S.u.k2s[d][0]);
      float4 kb = *reinterpret_cast<const float4*>(&S.u.k2s[d][4]);
      float s = ka.x * q2r[0] + ka.y * q2r[1] + ka.z * q2r[2] + ka.w * q2r[3]
              + kb.x * q2r[4] + kb.y * q2r[5] + kb.z * q2r[6] + kb.w * q2r[7];
      p[j] = __expf(s);
    }
#pragma unroll
    for (int j = 0; j < 4; ++j) {
      const int d = d0 + j;
      float t = p[j];
      t += __shfl_xor(t, 1, 64);
      t += __shfl_xor(t, 2, 64);
      t += __shfl_xor(t, 4, 64);
      t += __shfl_xor(t, 8, 64);
      t += __shfl_xor(t, 16, 64);
      t += __shfl_xor(t, 32, 64);
      float ip = p[j] * __builtin_amdgcn_rcpf(t);
      float4 va = *reinterpret_cast<const float4*>(&S.vvs[d][0]);
      float4 vb = *reinterpret_cast<const float4*>(&S.vvs[d][4]);
      out[0] += va.x * ip; out[1] += va.y * ip; out[2] += va.z * ip; out[3] += va.w * ip;
      out[4] += vb.x * ip; out[5] += vb.y * ip; out[6] += vb.z * ip; out[7] += vb.w * ip;
    }
  }

  // scramble store: scr[b][e*64 + n/64][(n%64)*8 + h], e = lane (16B/lane)
  uint32_t p0 = (uint32_t)f2b(out[0]) | ((uint32_t)f2b(out[1]) << 16);
  uint32_t p1 = (uint32_t)f2b(out[2]) | ((uint32_t)f2b(out[3]) << 16);
  uint32_t p2 = (uint32_t)f2b(out[4]) | ((uint32_t)f2b(out[5]) << 16);
  uint32_t p3 = (uint32_t)f2b(out[6]) | ((uint32_t)f2b(out[7]) << 16);
  uint4 pk; pk.x = p0; pk.y = p1; pk.z = p2; pk.w = p3;
  size_t doff = (size_t)b * 2097152 + ((size_t)lane * 64 + (size_t)(n >> 6)) * 512
              + (size_t)(n & 63) * 8;
  *reinterpret_cast<uint4*>(Sc + doff) = pk;
}

// ---------------- launcher ----------------
extern "C" void kernel_launch(void* const* d_in, const int* in_sizes, int n_in,
                              void* d_out, int out_size, void* d_ws, size_t ws_size,
                              hipStream_t stream) {
  const float* x  = (const float*)d_in[0];
  const float* Wq = (const float*)d_in[1];
  const float* Wk = (const float*)d_in[2];
  const float* Wv = (const float*)d_in[3];
  const float* Pw = (const float*)d_in[5];
  const float* Pb = (const float*)d_in[6];
  float* out = (float*)d_out;

  const size_t MK = 16384ull * 512ull;
  u16* Xb   = (u16*)d_ws;          // 16.8 MB
  u16* QKVb = Xb + MK;             // 50.3 MB (fused [16384][1536])
  u16* Scr  = QKVb + 3 * MK;       // 16.8 MB
  u16* Wcat = Scr + MK;            // 1.5 MB ([1536][512] = Wq|Wk|Wv)
  u16* Pwb  = Wcat + 3 * 262144;   // 0.5 MB

  cvt_kernel<<<8192, 256, 0, stream>>>(x,  Xb,   2097152);
  cvt_kernel<<<256,  256, 0, stream>>>(Wq, Wcat,          65536);
  cvt_kernel<<<256,  256, 0, stream>>>(Wk, Wcat + 262144, 65536);
  cvt_kernel<<<256,  256, 0, stream>>>(Wv, Wcat + 524288, 65536);
  cvt_kernel<<<256,  256, 0, stream>>>(Pw, Pwb,           65536);

  dim3 gq(12, 128);   // fused QKV: M=16384, N=1536, K=512
  gemm_bt<false><<<gq, 256, 0, stream>>>(Xb, Wcat, QKVb, nullptr, nullptr, 1536, 512);

  attn_pixel<<<4096, 256, 0, stream>>>(QKVb, Scr);

  dim3 gp(4, 128);
  gemm_bt<true><<<gp, 256, 0, stream>>>(Scr, Pwb, nullptr, out, Pb, 512, 512);
}